// Round 16
// baseline (231.322 us; speedup 1.0000x reference)
//
#include <hip/hip_runtime.h>

#define BB 2
#define NN 512
#define CC 256
#define OO 256
#define EE 18

// workspace layout (float offsets)
#define OFF_SF   0
#define OFF_NBR  (BB*NN*OO)
#define OFF_AI   (OFF_NBR + BB*NN*OO)
#define OFF_AJ   (OFF_AI + BB*NN*64)
#define OFF_EGX  (OFF_AJ + BB*NN*64)
#define OFF_MSG  (OFF_EGX + BB*NN*64)
// NBR stored TRANSPOSED [b][col][row]; AJ/EGX/AI/SF row-major.
// aliased weight-staging regions (lifetime-disjoint):
// WN in MSG region (prep -> k_node, clobbered later by k_edge MSG writes).
// W1/W2 in AI/AJ regions (prep_out runs AFTER k_edge).
// Edge-weight image lives in d_out (dead until k_out overwrites it).
#define OFF_WN   OFF_MSG
#define OFF_W1   OFF_AI
#define OFF_W2   OFF_AJ

typedef float f32x4 __attribute__((ext_vector_type(4)));
typedef __bf16 bf16x8 __attribute__((ext_vector_type(8)));

__device__ __forceinline__ unsigned short f2bf(float f) {
  unsigned u = __float_as_uint(f);
  u += 0x7fffu + ((u >> 16) & 1u);          // RNE
  return (unsigned short)(u >> 16);
}
__device__ __forceinline__ unsigned pk2(float a, float b) {
  return (unsigned)f2bf(a) | ((unsigned)f2bf(b) << 16);
}
__device__ __forceinline__ unsigned cvtpk(float a, float b) {
  unsigned r;
  asm("v_cvt_pk_bf16_f32 %0, %1, %2" : "=v"(r) : "v"(a), "v"(b));
  return r;   // lo = bf16(a), hi = bf16(b)
}
__device__ __forceinline__ int swzc(int chunk, int row) {
  return (chunk & ~7) | ((chunk ^ row) & 7);
}

__device__ __forceinline__ f32x4 mfma_bf16(uint4 a, uint4 b, f32x4 c) {
  return __builtin_amdgcn_mfma_f32_16x16x32_bf16(
      __builtin_bit_cast(bf16x8, a), __builtin_bit_cast(bf16x8, b), c, 0, 0, 0);
}

// ---------------------------------------------------------------------------
// k_prep_w: merged front-end weight prep (edge image -> d_out, node -> WN).
// ---------------------------------------------------------------------------
__global__ __launch_bounds__(256) void k_prep_w(
    const float* __restrict__ em_w1, const float* __restrict__ em_w2,
    const float* __restrict__ em_w3, const float* __restrict__ at_w1,
    const float* __restrict__ at_w2, const float* __restrict__ eg_w1,
    const float* __restrict__ eg_w2,
    const float* __restrict__ st_w,  const float* __restrict__ nt_w,
    unsigned char* __restrict__ img, float* __restrict__ ws)
{
  int bid = blockIdx.x;
  if (bid < 120) {
    int idx = bid * 256 + threadIdx.x;   // 0..30719
    const float* src; int KV, RO, k, l, ldw;
    if (idx < 2048)       { src = em_w1;          KV = 18; RO = 0;     k = idx>>6;  l = idx&63;  ldw = 64; }
    else if (idx < 6144)  { src = em_w2;          KV = 64; RO = 8192;  int e = idx-2048;  k = e>>6; l = e&63;  ldw = 64; }
    else if (idx < 8192)  { src = em_w3;          KV = 64; RO = 16384; int e = idx-6144;  k = e>>5; l = e&31;  ldw = 32; }
    else if (idx < 10240) { src = at_w1 + 512*64; KV = 32; RO = 20480; int e = idx-8192;  k = e>>6; l = e&63;  ldw = 64; }
    else if (idx < 12288) { src = at_w2;          KV = 64; RO = 28672; int e = idx-10240; k = e>>5; l = e&31;  ldw = 32; }
    else if (idx < 14336) { src = eg_w1 + 256*64; KV = 32; RO = 32768; int e = idx-12288; k = e>>6; l = e&63;  ldw = 64; }
    else                  { src = eg_w2;          KV = 64; RO = 40960; int e = idx-14336; k = e>>8; l = e&255; ldw = 256; }
    float v = (k < KV) ? src[(size_t)k*ldw + l] : 0.f;
    *(unsigned short*)(img + RO + l*128 + ((((k>>3) ^ (l&7))) << 4) + ((k&7) << 1)) = f2bf(v);
  } else {
    unsigned char* dst = (unsigned char*)(ws + OFF_WN);
    int idx = (bid - 120) * 256 + threadIdx.x;       // 704*32 = 22528
    int col = idx >> 5, ch = idx & 31;
    const float* src; int ld, c;
    if (col < 256)      { src = st_w;           ld = 256; c = col; }
    else if (col < 512) { src = nt_w;           ld = 256; c = col - 256; }
    else if (col < 576) { src = at_w1;          ld = 64;  c = col - 512; }
    else if (col < 640) { src = at_w1 + 256*64; ld = 64;  c = col - 576; }
    else                { src = eg_w1;          ld = 64;  c = col - 640; }
    float e[8];
    #pragma unroll
    for (int q = 0; q < 8; ++q) e[q] = src[(size_t)(ch*8+q)*ld + c];
    uint4 v = make_uint4(pk2(e[0],e[1]), pk2(e[2],e[3]), pk2(e[4],e[5]), pk2(e[6],e[7]));
    *(uint4*)(dst + (size_t)col*512 + swzc(ch, col)*16) = v;
  }
}

// ---------------------------------------------------------------------------
// prep_out: cb_w1 -> W1 [256 cols][512 k] bf16; cb_w2 -> W2 [256][256].
// ---------------------------------------------------------------------------
__global__ __launch_bounds__(256) void k_prep_out(
    const float* __restrict__ cb_w1, const float* __restrict__ cb_w2,
    float* __restrict__ ws)
{
  int bid = blockIdx.x;
  if (bid < 64) {
    unsigned char* dst = (unsigned char*)(ws + OFF_W1);
    int idx = bid * 256 + threadIdx.x;
    int col = idx >> 6, ch = idx & 63;
    float e[8];
    #pragma unroll
    for (int q = 0; q < 8; ++q) e[q] = cb_w1[(size_t)(ch*8+q)*256 + col];
    uint4 v = make_uint4(pk2(e[0],e[1]), pk2(e[2],e[3]), pk2(e[4],e[5]), pk2(e[6],e[7]));
    *(uint4*)(dst + (size_t)col*1024 + swzc(ch, col)*16) = v;
  } else {
    unsigned char* dst = (unsigned char*)(ws + OFF_W2);
    int idx = (bid - 64) * 256 + threadIdx.x;
    int col = idx >> 5, ch = idx & 31;
    float e[8];
    #pragma unroll
    for (int q = 0; q < 8; ++q) e[q] = cb_w2[(size_t)(ch*8+q)*256 + col];
    uint4 v = make_uint4(pk2(e[0],e[1]), pk2(e[2],e[3]), pk2(e[4],e[5]), pk2(e[6],e[7]));
    *(uint4*)(dst + (size_t)col*512 + swzc(ch, col)*16) = v;
  }
}

// ---------------------------------------------------------------------------
// k_node (MFMA, swapped operands): unchanged from round 8.
// ---------------------------------------------------------------------------
__global__ __launch_bounds__(256) void k_node(
    const float* __restrict__ x,
    const float* __restrict__ st_b, const float* __restrict__ nt_b,
    float* __restrict__ ws)
{
  __shared__ __align__(16) unsigned char sA[64*512];   // 32 KB
  const int t = threadIdx.x;
  const int c0 = blockIdx.x * 64, g0 = blockIdx.y * 64;

  for (int idx = t; idx < 64*64; idx += 256) {
    int row = idx >> 6, kq = idx & 63;
    float4 v = *(const float4*)(x + (size_t)(g0 + row)*CC + kq*4);
    uint2 p; p.x = pk2(v.x, v.y); p.y = pk2(v.z, v.w);
    *(uint2*)(sA + row*512 + swzc(kq >> 1, row)*16 + (kq & 1)*8) = p;
  }
  __syncthreads();

  const int wid = t >> 6, lane = t & 63, l4 = lane >> 4, l16 = lane & 15;
  const unsigned char* WN = (const unsigned char*)(ws + OFF_WN);

  uint4 af[8];
  {
    int row = wid*16 + l16;
    #pragma unroll
    for (int f = 0; f < 8; ++f)
      af[f] = *(const uint4*)(sA + row*512 + swzc(l4 + 4*f, row)*16);
  }

  const int grow = g0 + wid*16 + l16;
  const int bb = grow >> 9, n0 = grow & 511;

  #pragma unroll
  for (int ct = 0; ct < 4; ++ct) {
    int gcolL = c0 + ct*16 + l16;
    f32x4 acc = {0.f, 0.f, 0.f, 0.f};
    #pragma unroll
    for (int f = 0; f < 8; ++f) {
      uint4 wfr = *(const uint4*)(WN + (size_t)gcolL*512 + swzc(l4 + 4*f, gcolL)*16);
      acc = mfma_bf16(wfr, af[f], acc);
    }
    int gcol0 = c0 + ct*16 + l4*4;
    if (gcol0 < 256) {
      f32x4 bz = *(const f32x4*)(st_b + gcol0);
      f32x4 v = acc + bz;
      *(f32x4*)(ws + OFF_SF + (size_t)grow*OO + gcol0) = v;
    } else if (gcol0 < 512) {
      int c = gcol0 - 256;
      f32x4 bz = *(const f32x4*)(nt_b + c);
      #pragma unroll
      for (int r = 0; r < 4; ++r)
        ws[OFF_NBR + ((size_t)bb*256 + c + r)*512 + n0] = acc[r] + bz[r];
    } else if (gcol0 < 576) {
      *(f32x4*)(ws + OFF_AI + (size_t)grow*64 + (gcol0-512)) = acc;
    } else if (gcol0 < 640) {
      *(f32x4*)(ws + OFF_AJ + (size_t)grow*64 + (gcol0-576)) = acc;
    } else {
      *(f32x4*)(ws + OFF_EGX + (size_t)grow*64 + (gcol0-640)) = acc;
    }
  }
}

// ---------------------------------------------------------------------------
// k_edge: COMPACTED edge kernel. Masked j's (adj==0) contribute exactly zero
// (attn=0 multiplies both paths), so we compact the neighbor list first and
// run the whole pipeline only on real edges (expected ~256 of 512 -> ~2x less
// work). Tile = 16 compacted slots; wave w handles tiles w, w+8, ...
// Unnormalized softmax (verified R12). R8 fragment layout/swizzles unchanged.
// ---------------------------------------------------------------------------
__global__ __launch_bounds__(512, 2) void k_edge(
    const int*   __restrict__ adj,
    const float* __restrict__ ef_g,
    const unsigned char* __restrict__ wimg,
    const float* __restrict__ em_b1g, const float* __restrict__ em_b2g,
    const float* __restrict__ em_b3g,
    const float* __restrict__ at_b1g, const float* __restrict__ at_b2g,
    const float* __restrict__ at_w3g, const float* __restrict__ at_b3g,
    const float* __restrict__ eg_b1g, const float* __restrict__ eg_b2g,
    float* __restrict__ ws)
{
  __shared__ __align__(16) unsigned char s_act[512*128];   // 64 KB (compacted rows)
  __shared__ __align__(16) float s_bem1[64], s_bem2[64], s_bem3[32];
  __shared__ __align__(16) float s_t1init[64], s_bat2[32], s_w3[32];
  __shared__ __align__(16) float s_beg1[64], s_beg2[256];
  __shared__ __align__(16) float s_sc[512];        // unnormalized p per slot
  __shared__ __align__(16) float s_msg[8][256];    // per-wave msg partials
  __shared__ float s_red[8];
  __shared__ int   s_wcnt[8];
  __shared__ unsigned short s_jlist[512];

  const int t = threadIdx.x;
  const int i = blockIdx.x, b = blockIdx.y;
  const int wid = t >> 6, lane = t & 63, l4 = lane >> 4, l16 = lane & 15;

  const unsigned char* Wem1 = wimg;
  const unsigned char* Wem2 = wimg + 8192;
  const unsigned char* Wem3 = wimg + 16384;
  const unsigned char* Wat1 = wimg + 20480;
  const unsigned char* Wat2 = wimg + 28672;
  const unsigned char* Weg1 = wimg + 32768;
  const unsigned char* Weg2 = wimg + 40960;

  if (t < 64) {
    s_bem1[t]   = em_b1g[t];
    s_bem2[t]   = em_b2g[t];
    s_t1init[t] = ws[OFF_AI + (size_t)(b*NN + i)*64 + t] + at_b1g[t];
    s_beg1[t]   = eg_b1g[t];
  } else if (t < 96)  { s_bem3[t-64]  = em_b3g[t-64]; }
  else if (t < 128)   { s_bat2[t-96]  = at_b2g[t-96]; }
  else if (t < 160)   { s_w3[t-128]   = at_w3g[t-128]; }
  if (t < 256) s_beg2[t] = eg_b2g[t];
  const float atb3 = at_b3g[0];

  ((f32x4*)s_msg)[t] = (f32x4){0.f, 0.f, 0.f, 0.f};   // zero msg partials

  // ---------------- compaction: j's with adj>0 ----------------
  const bool me = adj[(size_t)(b*NN + i)*NN + t] > 0;
  unsigned long long bal = __ballot(me);
  if (lane == 0) s_wcnt[wid] = __popcll(bal);
  __syncthreads();                              // A: wcnt + biases visible
  int base = 0, tot = 0;
  #pragma unroll
  for (int w = 0; w < 8; ++w) { int c = s_wcnt[w]; tot += c; if (w < wid) base += c; }
  int prefix = __popcll(bal & ((1ull << lane) - 1ull));
  if (me) s_jlist[base + prefix] = (unsigned short)t;
  const int ntiles = (tot + 15) >> 4;
  const int nslots = ntiles << 4;
  __syncthreads();                              // B: jlist visible
  if (t < nslots - tot) s_jlist[tot + t] = s_jlist[0];   // pad dup (p zeroed below)
  __syncthreads();                              // C: pads visible

  auto loadA = [&](int rb, int f) -> uint4 {
    int rw = rb + l16;
    return *(const uint4*)(s_act + rw*128 + (((l4 + 4*f) ^ (rw & 7)) << 4));
  };
  auto loadB = [&](const unsigned char* w, int ct, int f) -> uint4 {
    int rw = ct*16 + l16;
    return *(const uint4*)(w + rw*128 + (((l4 + 4*f) ^ (rw & 7)) << 4));
  };
  auto storeCT = [&](int rb, int ct, const f32x4& c) {
    int rw = rb + l16;
    int col0 = ct*16 + l4*4;
    uint2 v;
    v.x = cvtpk(fmaxf(c[0], 0.f), fmaxf(c[1], 0.f));
    v.y = cvtpk(fmaxf(c[2], 0.f), fmaxf(c[3], 0.f));
    *(uint2*)(s_act + rw*128 + swzc(col0 >> 3, rw)*16 + (col0 & 7)*2) = v;
  };

  const float* ajR  = ws + OFF_AJ  + (size_t)b*NN*64;     // row-major [row][64]
  const float* egR  = ws + OFF_EGX + (size_t)b*NN*64;     // row-major [row][64]
  const float* nbrT = ws + OFF_NBR + (size_t)b*256*512;   // transposed [col][row]
  const float* efrow = ef_g + (size_t)(b*NN + i)*NN*EE;

  float denacc = 0.f;

  // ---------------- phase 1: per-wave compacted tiles ----------------
  #pragma unroll 1
  for (int tile = wid; tile < ntiles; tile += 8) {
    asm volatile("" ::: "memory");     // keep W-frag loads inside the loop
    const int SBs = tile << 4;

    // stage ef: 4 lanes per row (16 rows)
    {
      int rr = lane >> 2, cc = lane & 3;
      int s = SBs + rr;
      int jg = s_jlist[s];
      const float* efp = efrow + (size_t)jg * EE;
      uint4 u = make_uint4(0u, 0u, 0u, 0u);
      if (cc < 2) {
        float e[8];
        #pragma unroll
        for (int k = 0; k < 4; ++k) {
          float2 v2 = *(const float2*)(efp + cc*8 + 2*k);
          e[2*k] = v2.x; e[2*k+1] = v2.y;
        }
        u = make_uint4(pk2(e[0],e[1]), pk2(e[2],e[3]), pk2(e[4],e[5]), pk2(e[6],e[7]));
      } else if (cc == 2) {
        float2 v2 = *(const float2*)(efp + 16);
        u.x = pk2(v2.x, v2.y);
      }
      *(uint4*)(s_act + s*128 + ((cc ^ (s & 7)) << 4)) = u;
    }

    uint4 peA;

    // ---- L1: ef(K32) -> h1(64) ----
    {
      uint4 W[4];
      #pragma unroll
      for (int ct = 0; ct < 4; ++ct) W[ct] = loadB(Wem1, ct, 0);
      uint4 a = loadA(SBs, 0);
      #pragma unroll
      for (int ct = 0; ct < 4; ++ct) {
        f32x4 c = *(const f32x4*)&s_bem1[ct*16 + l4*4];
        c = mfma_bf16(W[ct], a, c);
        storeCT(SBs, ct, c);
      }
    }
    // ---- L2: h1(K64) -> h2(64) ----
    {
      uint4 W[4][2];
      #pragma unroll
      for (int ct = 0; ct < 4; ++ct) { W[ct][0] = loadB(Wem2, ct, 0); W[ct][1] = loadB(Wem2, ct, 1); }
      uint4 a0 = loadA(SBs, 0), a1 = loadA(SBs, 1);
      #pragma unroll
      for (int ct = 0; ct < 4; ++ct) {
        f32x4 c = *(const f32x4*)&s_bem2[ct*16 + l4*4];
        c = mfma_bf16(W[ct][0], a0, c);
        c = mfma_bf16(W[ct][1], a1, c);
        storeCT(SBs, ct, c);
      }
    }
    // ---- L3: h2(K64) -> pe(32); pe act-frag kept in a register ----
    {
      uint4 W[2][2];
      #pragma unroll
      for (int ct = 0; ct < 2; ++ct) { W[ct][0] = loadB(Wem3, ct, 0); W[ct][1] = loadB(Wem3, ct, 1); }
      uint4 a0 = loadA(SBs, 0), a1 = loadA(SBs, 1);
      #pragma unroll
      for (int ct = 0; ct < 2; ++ct) {
        f32x4 c = *(const f32x4*)&s_bem3[ct*16 + l4*4];
        c = mfma_bf16(W[ct][0], a0, c);
        c = mfma_bf16(W[ct][1], a1, c);
        storeCT(SBs, ct, c);
      }
      peA = loadA(SBs, 0);
    }
    // ---- L4a: t1 = relu(a_i + a_j + b1 + pe @ at_w1e) ----
    {
      int jg = s_jlist[SBs + l16];
      uint4 W[4];
      #pragma unroll
      for (int ct = 0; ct < 4; ++ct) W[ct] = loadB(Wat1, ct, 0);
      #pragma unroll
      for (int ct = 0; ct < 4; ++ct) {
        int col0 = ct*16 + l4*4;
        f32x4 ti = *(const f32x4*)&s_t1init[col0];
        f32x4 av = *(const f32x4*)(ajR + (size_t)jg*64 + col0);
        f32x4 c = ti + av;
        c = mfma_bf16(W[ct], peA, c);
        storeCT(SBs, ct, c);
      }
    }
    // ---- L5: t2 = relu(t1 @ at_w2 + b2); p = exp(score) (real slots only) ----
    {
      uint4 W[2][2];
      #pragma unroll
      for (int ct = 0; ct < 2; ++ct) { W[ct][0] = loadB(Wat2, ct, 0); W[ct][1] = loadB(Wat2, ct, 1); }
      uint4 a0 = loadA(SBs, 0), a1 = loadA(SBs, 1);
      f32x4 c0 = *(const f32x4*)&s_bat2[l4*4];
      f32x4 c1 = *(const f32x4*)&s_bat2[16 + l4*4];
      c0 = mfma_bf16(W[0][0], a0, c0); c0 = mfma_bf16(W[0][1], a1, c0);
      c1 = mfma_bf16(W[1][0], a0, c1); c1 = mfma_bf16(W[1][1], a1, c1);
      float val = 0.f;
      #pragma unroll
      for (int r = 0; r < 4; ++r) {
        val += fmaxf(c0[r], 0.f)*s_w3[l4*4 + r];
        val += fmaxf(c1[r], 0.f)*s_w3[16 + l4*4 + r];
      }
      val += __shfl_xor(val, 16);
      val += __shfl_xor(val, 32);
      if (l4 == 0) {
        int slot = SBs + l16;
        float pj = (slot < tot) ? __expf(val + atb3) : 0.f;
        s_sc[slot] = pj;
        denacc += pj;
      }
    }
    // ---- L4b: g1 = relu(eg_x_j + eg_b1 + pe @ eg_w1e) -> s_act ----
    {
      int jg = s_jlist[SBs + l16];
      uint4 W[4];
      #pragma unroll
      for (int ct = 0; ct < 4; ++ct) W[ct] = loadB(Weg1, ct, 0);
      #pragma unroll
      for (int ct = 0; ct < 4; ++ct) {
        int col0 = ct*16 + l4*4;
        f32x4 bg = *(const f32x4*)&s_beg1[col0];
        f32x4 ev = *(const f32x4*)(egR + (size_t)jg*64 + col0);
        f32x4 c = bg + ev;
        c = mfma_bf16(W[ct], peA, c);
        storeCT(SBs, ct, c);
      }
    }
  }

  // ---------------- denominator ----------------
  denacc += __shfl_xor(denacc, 1);  denacc += __shfl_xor(denacc, 2);
  denacc += __shfl_xor(denacc, 4);  denacc += __shfl_xor(denacc, 8);
  denacc += __shfl_xor(denacc, 16); denacc += __shfl_xor(denacc, 32);
  if (lane == 0) s_red[wid] = denacc;
  __syncthreads();                              // D: den partials visible
  float den = 0.f;
  #pragma unroll
  for (int w = 0; w < 8; ++w) den += s_red[w];
  const float inv = den > 0.f ? 1.f/den : 0.f;

  // ---------------- L7: z = g1 @ eg_w2 + b2; msg += sig(z) * p * nbr ----------------
  #pragma unroll 1
  for (int tile = wid; tile < ntiles; tile += 8) {
    asm volatile("" ::: "memory");
    const int SBs = tile << 4;
    uint4 gA0 = loadA(SBs, 0), gA1 = loadA(SBs, 1);
    int jr0 = s_jlist[SBs + l4*4 + 0];
    int jr1 = s_jlist[SBs + l4*4 + 1];
    int jr2 = s_jlist[SBs + l4*4 + 2];
    int jr3 = s_jlist[SBs + l4*4 + 3];
    f32x4 at = *(const f32x4*)&s_sc[SBs + l4*4];

    for (int ct = 0; ct < 16; ++ct) {
      uint4 B0 = loadB(Weg2, ct, 0), B1 = loadB(Weg2, ct, 1);
      int col = ct*16 + l16;
      float bz = s_beg2[col];
      f32x4 c = {bz, bz, bz, bz};
      c = mfma_bf16(gA0, B0, c);
      c = mfma_bf16(gA1, B1, c);
      const float* nb = nbrT + (size_t)col*512;
      float msgp;
      {
        float g0 = __builtin_amdgcn_rcpf(1.f + __expf(-c[0]));
        float g1 = __builtin_amdgcn_rcpf(1.f + __expf(-c[1]));
        float g2 = __builtin_amdgcn_rcpf(1.f + __expf(-c[2]));
        float g3 = __builtin_amdgcn_rcpf(1.f + __expf(-c[3]));
        msgp  = g0 * at[0] * nb[jr0];
        msgp += g1 * at[1] * nb[jr1];
        msgp += g2 * at[2] * nb[jr2];
        msgp += g3 * at[3] * nb[jr3];
      }
      msgp += __shfl_xor(msgp, 16);
      msgp += __shfl_xor(msgp, 32);
      if (lane < 16) s_msg[wid][ct*16 + lane] += msgp;
    }
  }
  __syncthreads();                              // E: msg partials visible
  if (t < 256) {
    float s = 0.f;
    #pragma unroll
    for (int w = 0; w < 8; ++w) s += s_msg[w][t];
    ws[OFF_MSG + (size_t)(b*NN + i)*OO + t] = s * inv;
  }
}

// ---------------------------------------------------------------------------
// k_out (MFMA): unchanged.
// ---------------------------------------------------------------------------
__global__ __launch_bounds__(256) void k_out(
    const float* __restrict__ cb_b1, const float* __restrict__ cb_b2,
    const float* __restrict__ ws, float* __restrict__ out)
{
  __shared__ __align__(16) unsigned char sA[16*1024];
  __shared__ __align__(16) unsigned char sT[16*512];
  const int t = threadIdx.x;
  const int g0 = blockIdx.x * 16;

  for (int idx = t; idx < 16*128; idx += 256) {
    int row = idx >> 7, kq = idx & 127;
    const float* src = (kq < 64)
        ? ws + OFF_SF  + (size_t)(g0 + row)*OO + kq*4
        : ws + OFF_MSG + (size_t)(g0 + row)*OO + (kq - 64)*4;
    float4 v = *(const float4*)src;
    uint2 p; p.x = pk2(v.x, v.y); p.y = pk2(v.z, v.w);
    *(uint2*)(sA + row*1024 + swzc(kq >> 1, row)*16 + (kq & 1)*8) = p;
  }
  __syncthreads();

  const int wid = t >> 6, lane = t & 63, l4 = lane >> 4, l16 = lane & 15;
  const unsigned char* W1 = (const unsigned char*)(ws + OFF_W1);
  const unsigned char* W2 = (const unsigned char*)(ws + OFF_W2);

  {
    uint4 af[16];
    #pragma unroll
    for (int f = 0; f < 16; ++f)
      af[f] = *(const uint4*)(sA + l16*1024 + swzc(l4 + 4*f, l16)*16);
    #pragma unroll
    for (int c = 0; c < 4; ++c) {
      int col = wid*64 + c*16 + l16;
      float bz = cb_b1[col];
      f32x4 acc = {bz, bz, bz, bz};
      #pragma unroll
      for (int f = 0; f < 16; ++f) {
        uint4 bfr = *(const uint4*)(W1 + (size_t)col*1024 + swzc(l4 + 4*f, col)*16);
        acc = mfma_bf16(af[f], bfr, acc);
      }
      #pragma unroll
      for (int r = 0; r < 4; ++r) {
        int row = l4*4 + r;
        *(unsigned short*)(sT + row*512 + swzc(col >> 3, row)*16 + (col & 7)*2)
            = f2bf(fmaxf(acc[r], 0.f));
      }
    }
  }
  __syncthreads();

  {
    uint4 tf[8];
    #pragma unroll
    for (int f = 0; f < 8; ++f)
      tf[f] = *(const uint4*)(sT + l16*512 + swzc(l4 + 4*f, l16)*16);
    #pragma unroll
    for (int c = 0; c < 4; ++c) {
      int col = wid*64 + c*16 + l16;
      float bz = cb_b2[col];
      f32x4 acc = {bz, bz, bz, bz};
      #pragma unroll
      for (int f = 0; f < 8; ++f) {
        uint4 bfr = *(const uint4*)(W2 + (size_t)col*512 + swzc(l4 + 4*f, col)*16);
        acc = mfma_bf16(tf[f], bfr, acc);
      }
      #pragma unroll
      for (int r = 0; r < 4; ++r)
        out[(size_t)(g0 + l4*4 + r)*OO + col] = acc[r];
    }
  }
}

extern "C" void kernel_launch(void* const* d_in, const int* in_sizes, int n_in,
                              void* d_out, int out_size, void* d_ws, size_t ws_size,
                              hipStream_t stream) {
  const float* x     = (const float*)d_in[0];
  const int*   adj   = (const int*)  d_in[1];
  const float* ef    = (const float*)d_in[2];
  const float* st_w  = (const float*)d_in[3];
  const float* st_b  = (const float*)d_in[4];
  const float* nt_w  = (const float*)d_in[5];
  const float* nt_b  = (const float*)d_in[6];
  const float* em_w1 = (const float*)d_in[7];
  const float* em_b1 = (const float*)d_in[8];
  const float* em_w2 = (const float*)d_in[9];
  const float* em_b2 = (const float*)d_in[10];
  const float* em_w3 = (const float*)d_in[11];
  const float* em_b3 = (const float*)d_in[12];
  const float* at_w1 = (const float*)d_in[13];
  const float* at_b1 = (const float*)d_in[14];
  const float* at_w2 = (const float*)d_in[15];
  const float* at_b2 = (const float*)d_in[16];
  const float* at_w3 = (const float*)d_in[17];
  const float* at_b3 = (const float*)d_in[18];
  const float* eg_w1 = (const float*)d_in[19];
  const float* eg_b1 = (const float*)d_in[20];
  const float* eg_w2 = (const float*)d_in[21];
  const float* eg_b2 = (const float*)d_in[22];
  const float* cb_w1 = (const float*)d_in[23];
  const float* cb_b1 = (const float*)d_in[24];
  const float* cb_w2 = (const float*)d_in[25];
  const float* cb_b2 = (const float*)d_in[26];
  float* ws  = (float*)d_ws;
  float* out = (float*)d_out;
  unsigned char* wimg = (unsigned char*)d_out;   // dead until k_out overwrites

  k_prep_w<<<dim3(208), dim3(256), 0, stream>>>(em_w1, em_w2, em_w3, at_w1, at_w2,
      eg_w1, eg_w2, st_w, nt_w, wimg, ws);
  k_node<<<dim3(11, 16), dim3(256), 0, stream>>>(x, st_b, nt_b, ws);
  k_edge<<<dim3(NN, BB), dim3(512), 0, stream>>>(adj, ef, wimg,
      em_b1, em_b2, em_b3, at_b1, at_b2, at_w3, at_b3, eg_b1, eg_b2, ws);
  k_prep_out<<<dim3(96), dim3(256), 0, stream>>>(cb_w1, cb_w2, ws);
  k_out<<<dim3(64), dim3(256), 0, stream>>>(cb_b1, cb_b2, ws, out);
}

// Round 17
// 140.855 us; speedup vs baseline: 1.6423x; 1.6423x over previous
//
#include <hip/hip_runtime.h>

#define BB 2
#define NN 512
#define CC 256
#define OO 256
#define EE 18

// workspace layout (float offsets)
#define OFF_SF   0
#define OFF_NBR  (BB*NN*OO)
#define OFF_AI   (OFF_NBR + BB*NN*OO)
#define OFF_AJ   (OFF_AI + BB*NN*64)
#define OFF_EGX  (OFF_AJ + BB*NN*64)
#define OFF_MSG  (OFF_EGX + BB*NN*64)
// NBR stored TRANSPOSED [b][col][row]; AJ/EGX/AI/SF row-major.
// aliased weight-staging regions (lifetime-disjoint):
// WN in MSG region (prep -> k_node, clobbered later by k_edge MSG writes).
// W1/W2 in AI/AJ regions (prep_out runs AFTER k_edge).
// Edge-weight image lives in d_out (dead until k_out overwrites it).
#define OFF_WN   OFF_MSG
#define OFF_W1   OFF_AI
#define OFF_W2   OFF_AJ

typedef float f32x4 __attribute__((ext_vector_type(4)));
typedef __bf16 bf16x8 __attribute__((ext_vector_type(8)));

__device__ __forceinline__ unsigned short f2bf(float f) {
  unsigned u = __float_as_uint(f);
  u += 0x7fffu + ((u >> 16) & 1u);          // RNE
  return (unsigned short)(u >> 16);
}
__device__ __forceinline__ unsigned pk2(float a, float b) {
  return (unsigned)f2bf(a) | ((unsigned)f2bf(b) << 16);
}
__device__ __forceinline__ unsigned cvtpk(float a, float b) {
  unsigned r;
  asm("v_cvt_pk_bf16_f32 %0, %1, %2" : "=v"(r) : "v"(a), "v"(b));
  return r;   // lo = bf16(a), hi = bf16(b)
}
__device__ __forceinline__ int swzc(int chunk, int row) {
  return (chunk & ~7) | ((chunk ^ row) & 7);
}

__device__ __forceinline__ f32x4 mfma_bf16(uint4 a, uint4 b, f32x4 c) {
  return __builtin_amdgcn_mfma_f32_16x16x32_bf16(
      __builtin_bit_cast(bf16x8, a), __builtin_bit_cast(bf16x8, b), c, 0, 0, 0);
}

// ---------------------------------------------------------------------------
// k_prep_w: merged front-end weight prep (edge image -> d_out, node -> WN).
// ---------------------------------------------------------------------------
__global__ __launch_bounds__(256) void k_prep_w(
    const float* __restrict__ em_w1, const float* __restrict__ em_w2,
    const float* __restrict__ em_w3, const float* __restrict__ at_w1,
    const float* __restrict__ at_w2, const float* __restrict__ eg_w1,
    const float* __restrict__ eg_w2,
    const float* __restrict__ st_w,  const float* __restrict__ nt_w,
    unsigned char* __restrict__ img, float* __restrict__ ws)
{
  int bid = blockIdx.x;
  if (bid < 120) {
    int idx = bid * 256 + threadIdx.x;   // 0..30719
    const float* src; int KV, RO, k, l, ldw;
    if (idx < 2048)       { src = em_w1;          KV = 18; RO = 0;     k = idx>>6;  l = idx&63;  ldw = 64; }
    else if (idx < 6144)  { src = em_w2;          KV = 64; RO = 8192;  int e = idx-2048;  k = e>>6; l = e&63;  ldw = 64; }
    else if (idx < 8192)  { src = em_w3;          KV = 64; RO = 16384; int e = idx-6144;  k = e>>5; l = e&31;  ldw = 32; }
    else if (idx < 10240) { src = at_w1 + 512*64; KV = 32; RO = 20480; int e = idx-8192;  k = e>>6; l = e&63;  ldw = 64; }
    else if (idx < 12288) { src = at_w2;          KV = 64; RO = 28672; int e = idx-10240; k = e>>5; l = e&31;  ldw = 32; }
    else if (idx < 14336) { src = eg_w1 + 256*64; KV = 32; RO = 32768; int e = idx-12288; k = e>>6; l = e&63;  ldw = 64; }
    else                  { src = eg_w2;          KV = 64; RO = 40960; int e = idx-14336; k = e>>8; l = e&255; ldw = 256; }
    float v = (k < KV) ? src[(size_t)k*ldw + l] : 0.f;
    *(unsigned short*)(img + RO + l*128 + ((((k>>3) ^ (l&7))) << 4) + ((k&7) << 1)) = f2bf(v);
  } else {
    unsigned char* dst = (unsigned char*)(ws + OFF_WN);
    int idx = (bid - 120) * 256 + threadIdx.x;       // 704*32 = 22528
    int col = idx >> 5, ch = idx & 31;
    const float* src; int ld, c;
    if (col < 256)      { src = st_w;           ld = 256; c = col; }
    else if (col < 512) { src = nt_w;           ld = 256; c = col - 256; }
    else if (col < 576) { src = at_w1;          ld = 64;  c = col - 512; }
    else if (col < 640) { src = at_w1 + 256*64; ld = 64;  c = col - 576; }
    else                { src = eg_w1;          ld = 64;  c = col - 640; }
    float e[8];
    #pragma unroll
    for (int q = 0; q < 8; ++q) e[q] = src[(size_t)(ch*8+q)*ld + c];
    uint4 v = make_uint4(pk2(e[0],e[1]), pk2(e[2],e[3]), pk2(e[4],e[5]), pk2(e[6],e[7]));
    *(uint4*)(dst + (size_t)col*512 + swzc(ch, col)*16) = v;
  }
}

// ---------------------------------------------------------------------------
// prep_out: cb_w1 -> W1 [256 cols][512 k] bf16; cb_w2 -> W2 [256][256].
// ---------------------------------------------------------------------------
__global__ __launch_bounds__(256) void k_prep_out(
    const float* __restrict__ cb_w1, const float* __restrict__ cb_w2,
    float* __restrict__ ws)
{
  int bid = blockIdx.x;
  if (bid < 64) {
    unsigned char* dst = (unsigned char*)(ws + OFF_W1);
    int idx = bid * 256 + threadIdx.x;
    int col = idx >> 6, ch = idx & 63;
    float e[8];
    #pragma unroll
    for (int q = 0; q < 8; ++q) e[q] = cb_w1[(size_t)(ch*8+q)*256 + col];
    uint4 v = make_uint4(pk2(e[0],e[1]), pk2(e[2],e[3]), pk2(e[4],e[5]), pk2(e[6],e[7]));
    *(uint4*)(dst + (size_t)col*1024 + swzc(ch, col)*16) = v;
  } else {
    unsigned char* dst = (unsigned char*)(ws + OFF_W2);
    int idx = (bid - 64) * 256 + threadIdx.x;
    int col = idx >> 5, ch = idx & 31;
    float e[8];
    #pragma unroll
    for (int q = 0; q < 8; ++q) e[q] = cb_w2[(size_t)(ch*8+q)*256 + col];
    uint4 v = make_uint4(pk2(e[0],e[1]), pk2(e[2],e[3]), pk2(e[4],e[5]), pk2(e[6],e[7]));
    *(uint4*)(dst + (size_t)col*512 + swzc(ch, col)*16) = v;
  }
}

// ---------------------------------------------------------------------------
// k_node (MFMA, swapped operands): unchanged from round 8.
// ---------------------------------------------------------------------------
__global__ __launch_bounds__(256) void k_node(
    const float* __restrict__ x,
    const float* __restrict__ st_b, const float* __restrict__ nt_b,
    float* __restrict__ ws)
{
  __shared__ __align__(16) unsigned char sA[64*512];   // 32 KB
  const int t = threadIdx.x;
  const int c0 = blockIdx.x * 64, g0 = blockIdx.y * 64;

  for (int idx = t; idx < 64*64; idx += 256) {
    int row = idx >> 6, kq = idx & 63;
    float4 v = *(const float4*)(x + (size_t)(g0 + row)*CC + kq*4);
    uint2 p; p.x = pk2(v.x, v.y); p.y = pk2(v.z, v.w);
    *(uint2*)(sA + row*512 + swzc(kq >> 1, row)*16 + (kq & 1)*8) = p;
  }
  __syncthreads();

  const int wid = t >> 6, lane = t & 63, l4 = lane >> 4, l16 = lane & 15;
  const unsigned char* WN = (const unsigned char*)(ws + OFF_WN);

  uint4 af[8];
  {
    int row = wid*16 + l16;
    #pragma unroll
    for (int f = 0; f < 8; ++f)
      af[f] = *(const uint4*)(sA + row*512 + swzc(l4 + 4*f, row)*16);
  }

  const int grow = g0 + wid*16 + l16;
  const int bb = grow >> 9, n0 = grow & 511;

  #pragma unroll
  for (int ct = 0; ct < 4; ++ct) {
    int gcolL = c0 + ct*16 + l16;
    f32x4 acc = {0.f, 0.f, 0.f, 0.f};
    #pragma unroll
    for (int f = 0; f < 8; ++f) {
      uint4 wfr = *(const uint4*)(WN + (size_t)gcolL*512 + swzc(l4 + 4*f, gcolL)*16);
      acc = mfma_bf16(wfr, af[f], acc);
    }
    int gcol0 = c0 + ct*16 + l4*4;
    if (gcol0 < 256) {
      f32x4 bz = *(const f32x4*)(st_b + gcol0);
      f32x4 v = acc + bz;
      *(f32x4*)(ws + OFF_SF + (size_t)grow*OO + gcol0) = v;
    } else if (gcol0 < 512) {
      int c = gcol0 - 256;
      f32x4 bz = *(const f32x4*)(nt_b + c);
      #pragma unroll
      for (int r = 0; r < 4; ++r)
        ws[OFF_NBR + ((size_t)bb*256 + c + r)*512 + n0] = acc[r] + bz[r];
    } else if (gcol0 < 576) {
      *(f32x4*)(ws + OFF_AI + (size_t)grow*64 + (gcol0-512)) = acc;
    } else if (gcol0 < 640) {
      *(f32x4*)(ws + OFF_AJ + (size_t)grow*64 + (gcol0-576)) = acc;
    } else {
      *(f32x4*)(ws + OFF_EGX + (size_t)grow*64 + (gcol0-640)) = acc;
    }
  }
}

// ---------------------------------------------------------------------------
// k_edge: the verified R15 kernel (123 us, VGPR 64, 78 KB LDS, 2 blocks/CU,
// 43% occupancy). Full-MFMA, swapped operands L1-L5, full-block softmax,
// L7 in original orientation. All alternatives falsified by measurement:
// streaming s_act (regs 100-128 -> spill/1-block), compaction (VGPR 84
// occupancy cliff + lost W-load amortization).
// ---------------------------------------------------------------------------
__global__ __launch_bounds__(512, 2) void k_edge(
    const int*   __restrict__ adj,
    const float* __restrict__ ef_g,
    const unsigned char* __restrict__ wimg,
    const float* __restrict__ em_b1g, const float* __restrict__ em_b2g,
    const float* __restrict__ em_b3g,
    const float* __restrict__ at_b1g, const float* __restrict__ at_b2g,
    const float* __restrict__ at_w3g, const float* __restrict__ at_b3g,
    const float* __restrict__ eg_b1g, const float* __restrict__ eg_b2g,
    float* __restrict__ ws)
{
  __shared__ __align__(16) unsigned char s_act[512*128];   // 64 KB activation bounce
  __shared__ __align__(16) float s_bem1[64], s_bem2[64], s_bem3[32];
  __shared__ __align__(16) float s_t1init[64], s_bat2[32], s_w3[32];
  __shared__ __align__(16) float s_beg1[64], s_beg2[256];
  __shared__ __align__(16) float s_sc[512];
  __shared__ float s_red[8];
  __shared__ float s_msg[8][256];

  const int t = threadIdx.x;
  const int i = blockIdx.x, b = blockIdx.y;
  const int wid = t >> 6, lane = t & 63, l4 = lane >> 4, l16 = lane & 15;
  const int R = wid * 64;

  const unsigned char* Wem1 = wimg;
  const unsigned char* Wem2 = wimg + 8192;
  const unsigned char* Wem3 = wimg + 16384;
  const unsigned char* Wat1 = wimg + 20480;
  const unsigned char* Wat2 = wimg + 28672;
  const unsigned char* Weg1 = wimg + 32768;
  const unsigned char* Weg2 = wimg + 40960;

  if (t < 64) {
    s_bem1[t]   = em_b1g[t];
    s_bem2[t]   = em_b2g[t];
    s_t1init[t] = ws[OFF_AI + (size_t)(b*NN + i)*64 + t] + at_b1g[t];
    s_beg1[t]   = eg_b1g[t];
  } else if (t < 96)  { s_bem3[t-64]  = em_b3g[t-64]; }
  else if (t < 128)   { s_bat2[t-96]  = at_b2g[t-96]; }
  else if (t < 160)   { s_w3[t-128]   = at_w3g[t-128]; }
  if (t < 256) s_beg2[t] = eg_b2g[t];
  const float atb3 = at_b3g[0];

  const float maskf = adj[(size_t)(b*NN + i)*NN + t] > 0 ? 1.f : 0.f;

  // stage ef row (pad 18 -> 32, bf16, swizzled)
  {
    const int j = t;
    const float* efp = ef_g + ((size_t)(b*NN + i)*NN + j) * EE;
    float e[32];
    #pragma unroll
    for (int k = 0; k < 9; ++k) { float2 v2 = *(const float2*)(efp + 2*k); e[2*k] = v2.x; e[2*k+1] = v2.y; }
    #pragma unroll
    for (int k = EE; k < 32; ++k) e[k] = 0.f;
    #pragma unroll
    for (int c = 0; c < 4; ++c) {
      uint4 u = make_uint4(pk2(e[c*8+0],e[c*8+1]), pk2(e[c*8+2],e[c*8+3]),
                           pk2(e[c*8+4],e[c*8+5]), pk2(e[c*8+6],e[c*8+7]));
      *(uint4*)(s_act + j*128 + ((c ^ (j & 7)) << 4)) = u;
    }
  }
  __syncthreads();

  auto loadA = [&](int rb, int f) -> uint4 {      // act fragment (B operand for L1-L5)
    int rw = rb + l16;
    return *(const uint4*)(s_act + rw*128 + (((l4 + 4*f) ^ (rw & 7)) << 4));
  };
  auto loadB = [&](const unsigned char* w, int ct, int f) -> uint4 {  // weight frag
    int rw = ct*16 + l16;
    return *(const uint4*)(w + rw*128 + (((l4 + 4*f) ^ (rw & 7)) << 4));
  };
  // swapped-C store: thread holds row j = rb+l16, cols ct*16+l4*4 .. +3
  auto storeCT = [&](int rb, int ct, const f32x4& c) {
    int rw = rb + l16;
    int col0 = ct*16 + l4*4;
    uint2 v;
    v.x = cvtpk(fmaxf(c[0], 0.f), fmaxf(c[1], 0.f));
    v.y = cvtpk(fmaxf(c[2], 0.f), fmaxf(c[3], 0.f));
    *(uint2*)(s_act + rw*128 + swzc(col0 >> 3, rw)*16 + (col0 & 7)*2) = v;
  };

  const float* ajR  = ws + OFF_AJ  + (size_t)b*NN*64;     // row-major [row][64]
  const float* egR  = ws + OFF_EGX + (size_t)b*NN*64;     // row-major [row][64]
  const float* nbrT = ws + OFF_NBR + (size_t)b*256*512;   // transposed [col][row]

  uint4 peA[4];

  // ---- L1: ef(K32) -> h1(64) ----
  {
    uint4 W[4];
    #pragma unroll
    for (int ct = 0; ct < 4; ++ct) W[ct] = loadB(Wem1, ct, 0);
    #pragma unroll
    for (int st = 0; st < 4; ++st) {
      int rb = R + st*16;
      uint4 a = loadA(rb, 0);
      #pragma unroll
      for (int ct = 0; ct < 4; ++ct) {
        f32x4 c = *(const f32x4*)&s_bem1[ct*16 + l4*4];
        c = mfma_bf16(W[ct], a, c);
        storeCT(rb, ct, c);
      }
    }
  }
  // ---- L2: h1(K64) -> h2(64) ----
  {
    uint4 W[4][2];
    #pragma unroll
    for (int ct = 0; ct < 4; ++ct) { W[ct][0] = loadB(Wem2, ct, 0); W[ct][1] = loadB(Wem2, ct, 1); }
    #pragma unroll
    for (int st = 0; st < 4; ++st) {
      int rb = R + st*16;
      uint4 a0 = loadA(rb, 0), a1 = loadA(rb, 1);
      #pragma unroll
      for (int ct = 0; ct < 4; ++ct) {
        f32x4 c = *(const f32x4*)&s_bem2[ct*16 + l4*4];
        c = mfma_bf16(W[ct][0], a0, c);
        c = mfma_bf16(W[ct][1], a1, c);
        storeCT(rb, ct, c);
      }
    }
  }
  // ---- L3: h2(K64) -> pe(32); keep pe act-frags in registers ----
  {
    uint4 W[2][2];
    #pragma unroll
    for (int ct = 0; ct < 2; ++ct) { W[ct][0] = loadB(Wem3, ct, 0); W[ct][1] = loadB(Wem3, ct, 1); }
    #pragma unroll
    for (int st = 0; st < 4; ++st) {
      int rb = R + st*16;
      uint4 a0 = loadA(rb, 0), a1 = loadA(rb, 1);
      #pragma unroll
      for (int ct = 0; ct < 2; ++ct) {
        f32x4 c = *(const f32x4*)&s_bem3[ct*16 + l4*4];
        c = mfma_bf16(W[ct][0], a0, c);
        c = mfma_bf16(W[ct][1], a1, c);
        storeCT(rb, ct, c);
      }
      peA[st] = loadA(rb, 0);
    }
  }
  // ---- L4a: t1 = relu(a_i + a_j + b1 + pe @ at_w1e) ----
  {
    uint4 W[4];
    #pragma unroll
    for (int ct = 0; ct < 4; ++ct) W[ct] = loadB(Wat1, ct, 0);
    #pragma unroll
    for (int st = 0; st < 4; ++st) {
      int rb = R + st*16;
      int j = rb + l16;
      #pragma unroll
      for (int ct = 0; ct < 4; ++ct) {
        int col0 = ct*16 + l4*4;
        f32x4 ti = *(const f32x4*)&s_t1init[col0];
        f32x4 av = *(const f32x4*)(ajR + (size_t)j*64 + col0);
        f32x4 c = ti + av;
        c = mfma_bf16(W[ct], peA[st], c);
        storeCT(rb, ct, c);
      }
    }
  }
  // ---- L5: t2 = relu(t1 @ at_w2 + b2); score = t2 . w3 + b3 ----
  {
    uint4 W[2][2];
    #pragma unroll
    for (int ct = 0; ct < 2; ++ct) { W[ct][0] = loadB(Wat2, ct, 0); W[ct][1] = loadB(Wat2, ct, 1); }
    #pragma unroll
    for (int st = 0; st < 4; ++st) {
      int rb = R + st*16;
      uint4 a0 = loadA(rb, 0), a1 = loadA(rb, 1);
      f32x4 c0 = *(const f32x4*)&s_bat2[l4*4];
      f32x4 c1 = *(const f32x4*)&s_bat2[16 + l4*4];
      c0 = mfma_bf16(W[0][0], a0, c0); c0 = mfma_bf16(W[0][1], a1, c0);
      c1 = mfma_bf16(W[1][0], a0, c1); c1 = mfma_bf16(W[1][1], a1, c1);
      float val = 0.f;
      #pragma unroll
      for (int r = 0; r < 4; ++r) {
        val += fmaxf(c0[r], 0.f)*s_w3[l4*4 + r];
        val += fmaxf(c1[r], 0.f)*s_w3[16 + l4*4 + r];
      }
      val += __shfl_xor(val, 16);
      val += __shfl_xor(val, 32);
      if (l4 == 0) s_sc[rb + l16] = val + atb3;
    }
  }
  // ---- L4b: g1 = relu(eg_x_j + eg_b1 + pe @ eg_w1e) -> s_act ----
  {
    uint4 W[4];
    #pragma unroll
    for (int ct = 0; ct < 4; ++ct) W[ct] = loadB(Weg1, ct, 0);
    #pragma unroll
    for (int st = 0; st < 4; ++st) {
      int rb = R + st*16;
      int j = rb + l16;
      #pragma unroll
      for (int ct = 0; ct < 4; ++ct) {
        int col0 = ct*16 + l4*4;
        f32x4 bg = *(const f32x4*)&s_beg1[col0];
        f32x4 ev = *(const f32x4*)(egR + (size_t)j*64 + col0);
        f32x4 c = bg + ev;
        c = mfma_bf16(W[ct], peA[st], c);
        storeCT(rb, ct, c);
      }
    }
  }
  __syncthreads();

  // ---------------- masked softmax over j ----------------
  {
    float v  = maskf > 0.f ? s_sc[t] : -1e9f;
    float m = v;
    #pragma unroll
    for (int d = 1; d < 64; d <<= 1) m = fmaxf(m, __shfl_xor(m, d));
    if (lane == 0) s_red[wid] = m;
    __syncthreads();
    float mx = s_red[0];
    #pragma unroll
    for (int w = 1; w < 8; ++w) mx = fmaxf(mx, s_red[w]);
    float p = maskf > 0.f ? __expf(v - mx) : 0.f;
    float sm = p;
    #pragma unroll
    for (int d = 1; d < 64; d <<= 1) sm += __shfl_xor(sm, d);
    __syncthreads();
    if (lane == 0) s_red[wid] = sm;
    __syncthreads();
    float den = 0.f;
    #pragma unroll
    for (int w = 0; w < 8; ++w) den += s_red[w];
    float inv = den > 0.f ? 1.f/den : 0.f;
    s_sc[t] = p * inv;
  }
  __syncthreads();

  // ---- L7 (original orientation): z = g1 @ eg_w2 + b2; msg += sig(z)*attn*nbr ----
  {
    uint4 gA[4][2];
    #pragma unroll
    for (int st = 0; st < 4; ++st) { gA[st][0] = loadA(R + st*16, 0); gA[st][1] = loadA(R + st*16, 1); }

    for (int ct = 0; ct < 16; ++ct) {
      uint4 B0 = loadB(Weg2, ct, 0), B1 = loadB(Weg2, ct, 1);
      int col = ct*16 + l16;
      float bz = s_beg2[col];
      const float* nbrc = nbrT + (size_t)col*512 + R + l4*4;
      float msgp = 0.f;
      #pragma unroll
      for (int st = 0; st < 4; ++st) {
        f32x4 nv = *(const f32x4*)(nbrc + st*16);
        f32x4 at = *(const f32x4*)(&s_sc[R + st*16 + l4*4]);
        f32x4 c = {bz, bz, bz, bz};
        c = mfma_bf16(gA[st][0], B0, c);
        c = mfma_bf16(gA[st][1], B1, c);
        #pragma unroll
        for (int r = 0; r < 4; ++r) {
          float g = __builtin_amdgcn_rcpf(1.f + __expf(-c[r]));
          msgp += g * at[r] * nv[r];
        }
      }
      msgp += __shfl_xor(msgp, 16);
      msgp += __shfl_xor(msgp, 32);
      if (lane < 16) s_msg[wid][ct*16 + lane] = msgp;
    }
  }
  __syncthreads();
  if (t < 256) {
    float s = 0.f;
    #pragma unroll
    for (int w = 0; w < 8; ++w) s += s_msg[w][t];
    ws[OFF_MSG + (size_t)(b*NN + i)*OO + t] = s;
  }
}

// ---------------------------------------------------------------------------
// k_out (MFMA): unchanged.
// ---------------------------------------------------------------------------
__global__ __launch_bounds__(256) void k_out(
    const float* __restrict__ cb_b1, const float* __restrict__ cb_b2,
    const float* __restrict__ ws, float* __restrict__ out)
{
  __shared__ __align__(16) unsigned char sA[16*1024];
  __shared__ __align__(16) unsigned char sT[16*512];
  const int t = threadIdx.x;
  const int g0 = blockIdx.x * 16;

  for (int idx = t; idx < 16*128; idx += 256) {
    int row = idx >> 7, kq = idx & 127;
    const float* src = (kq < 64)
        ? ws + OFF_SF  + (size_t)(g0 + row)*OO + kq*4
        : ws + OFF_MSG + (size_t)(g0 + row)*OO + (kq - 64)*4;
    float4 v = *(const float4*)src;
    uint2 p; p.x = pk2(v.x, v.y); p.y = pk2(v.z, v.w);
    *(uint2*)(sA + row*1024 + swzc(kq >> 1, row)*16 + (kq & 1)*8) = p;
  }
  __syncthreads();

  const int wid = t >> 6, lane = t & 63, l4 = lane >> 4, l16 = lane & 15;
  const unsigned char* W1 = (const unsigned char*)(ws + OFF_W1);
  const unsigned char* W2 = (const unsigned char*)(ws + OFF_W2);

  {
    uint4 af[16];
    #pragma unroll
    for (int f = 0; f < 16; ++f)
      af[f] = *(const uint4*)(sA + l16*1024 + swzc(l4 + 4*f, l16)*16);
    #pragma unroll
    for (int c = 0; c < 4; ++c) {
      int col = wid*64 + c*16 + l16;
      float bz = cb_b1[col];
      f32x4 acc = {bz, bz, bz, bz};
      #pragma unroll
      for (int f = 0; f < 16; ++f) {
        uint4 bfr = *(const uint4*)(W1 + (size_t)col*1024 + swzc(l4 + 4*f, col)*16);
        acc = mfma_bf16(af[f], bfr, acc);
      }
      #pragma unroll
      for (int r = 0; r < 4; ++r) {
        int row = l4*4 + r;
        *(unsigned short*)(sT + row*512 + swzc(col >> 3, row)*16 + (col & 7)*2)
            = f2bf(fmaxf(acc[r], 0.f));
      }
    }
  }
  __syncthreads();

  {
    uint4 tf[8];
    #pragma unroll
    for (int f = 0; f < 8; ++f)
      tf[f] = *(const uint4*)(sT + l16*512 + swzc(l4 + 4*f, l16)*16);
    #pragma unroll
    for (int c = 0; c < 4; ++c) {
      int col = wid*64 + c*16 + l16;
      float bz = cb_b2[col];
      f32x4 acc = {bz, bz, bz, bz};
      #pragma unroll
      for (int f = 0; f < 8; ++f) {
        uint4 bfr = *(const uint4*)(W2 + (size_t)col*512 + swzc(l4 + 4*f, col)*16);
        acc = mfma_bf16(tf[f], bfr, acc);
      }
      #pragma unroll
      for (int r = 0; r < 4; ++r)
        out[(size_t)(g0 + l4*4 + r)*OO + col] = acc[r];
    }
  }
}

extern "C" void kernel_launch(void* const* d_in, const int* in_sizes, int n_in,
                              void* d_out, int out_size, void* d_ws, size_t ws_size,
                              hipStream_t stream) {
  const float* x     = (const float*)d_in[0];
  const int*   adj   = (const int*)  d_in[1];
  const float* ef    = (const float*)d_in[2];
  const float* st_w  = (const float*)d_in[3];
  const float* st_b  = (const float*)d_in[4];
  const float* nt_w  = (const float*)d_in[5];
  const float* nt_b  = (const float*)d_in[6];
  const float* em_w1 = (const float*)d_in[7];
  const float* em_b1 = (const float*)d_in[8];
  const float* em_w2 = (const float*)d_in[9];
  const float* em_b2 = (const float*)d_in[10];
  const float* em_w3 = (const float*)d_in[11];
  const float* em_b3 = (const float*)d_in[12];
  const float* at_w1 = (const float*)d_in[13];
  const float* at_b1 = (const float*)d_in[14];
  const float* at_w2 = (const float*)d_in[15];
  const float* at_b2 = (const float*)d_in[16];
  const float* at_w3 = (const float*)d_in[17];
  const float* at_b3 = (const float*)d_in[18];
  const float* eg_w1 = (const float*)d_in[19];
  const float* eg_b1 = (const float*)d_in[20];
  const float* eg_w2 = (const float*)d_in[21];
  const float* eg_b2 = (const float*)d_in[22];
  const float* cb_w1 = (const float*)d_in[23];
  const float* cb_b1 = (const float*)d_in[24];
  const float* cb_w2 = (const float*)d_in[25];
  const float* cb_b2 = (const float*)d_in[26];
  float* ws  = (float*)d_ws;
  float* out = (float*)d_out;
  unsigned char* wimg = (unsigned char*)d_out;   // dead until k_out overwrites

  k_prep_w<<<dim3(208), dim3(256), 0, stream>>>(em_w1, em_w2, em_w3, at_w1, at_w2,
      eg_w1, eg_w2, st_w, nt_w, wimg, ws);
  k_node<<<dim3(11, 16), dim3(256), 0, stream>>>(x, st_b, nt_b, ws);
  k_edge<<<dim3(NN, BB), dim3(512), 0, stream>>>(adj, ef, wimg,
      em_b1, em_b2, em_b3, at_b1, at_b2, at_w3, at_b3, eg_b1, eg_b2, ws);
  k_prep_out<<<dim3(96), dim3(256), 0, stream>>>(cb_w1, cb_w2, ws);
  k_out<<<dim3(64), dim3(256), 0, stream>>>(cb_b1, cb_b2, ws, out);
}